// Round 1
// baseline (746.916 us; speedup 1.0000x reference)
//
#include <hip/hip_runtime.h>
#include <stdint.h>

#define BATCH 128
#define SEQL  512
#define FDIM  768
#define CTAGS 52
#define START_IDX 50
#define STOP_IDX  51
#define NEG_INF (-3.4e38f)

// ---------------------------------------------------------------------------
// K1: emission GEMM  emit[(b*L+l)][c] = sum_f features[b,l,f] * W[c,f] + bias[c]
// Tiled fp32: BM=64 rows, BN=64 (tags padded 52->64), BK=64.
// ---------------------------------------------------------------------------
#define BM 64
#define BN 64
#define BK 64

__global__ __launch_bounds__(256) void emit_gemm(
    const float* __restrict__ F, const float* __restrict__ W,
    const float* __restrict__ bias, float* __restrict__ emit)
{
    __shared__ float Fs[BM][BK + 4];
    __shared__ float Ws[BN][BK + 4];

    const int tid  = threadIdx.x;
    const int row0 = blockIdx.x * BM;
    const int tr = tid >> 4;   // 0..15
    const int tc = tid & 15;   // 0..15

    float acc[4][4];
#pragma unroll
    for (int i = 0; i < 4; ++i)
#pragma unroll
        for (int j = 0; j < 4; ++j) acc[i][j] = 0.f;

    for (int k0 = 0; k0 < FDIM; k0 += BK) {
        // load tiles: each thread loads 4 float4 of F and 4 float4 of W
#pragma unroll
        for (int i = 0; i < 4; ++i) {
            int rr = tr + 16 * i;
            float4 fv = *(const float4*)&F[(size_t)(row0 + rr) * FDIM + k0 + tc * 4];
            *(float4*)&Fs[rr][tc * 4] = fv;
            float4 wv;
            if (rr < CTAGS) wv = *(const float4*)&W[(size_t)rr * FDIM + k0 + tc * 4];
            else            wv = make_float4(0.f, 0.f, 0.f, 0.f);
            *(float4*)&Ws[rr][tc * 4] = wv;
        }
        __syncthreads();

#pragma unroll
        for (int kk = 0; kk < BK; kk += 4) {
            float4 a[4], bb[4];
#pragma unroll
            for (int i = 0; i < 4; ++i) a[i]  = *(const float4*)&Fs[tr + 16 * i][kk];
#pragma unroll
            for (int j = 0; j < 4; ++j) bb[j] = *(const float4*)&Ws[tc + 16 * j][kk];
#pragma unroll
            for (int i = 0; i < 4; ++i)
#pragma unroll
                for (int j = 0; j < 4; ++j) {
                    acc[i][j] = fmaf(a[i].x, bb[j].x, acc[i][j]);
                    acc[i][j] = fmaf(a[i].y, bb[j].y, acc[i][j]);
                    acc[i][j] = fmaf(a[i].z, bb[j].z, acc[i][j]);
                    acc[i][j] = fmaf(a[i].w, bb[j].w, acc[i][j]);
                }
        }
        __syncthreads();
    }

#pragma unroll
    for (int j = 0; j < 4; ++j) {
        int c = tc + 16 * j;
        if (c < CTAGS) {
            float bv = bias[c];
#pragma unroll
            for (int i = 0; i < 4; ++i) {
                int r = row0 + tr + 16 * i;
                emit[(size_t)r * CTAGS + c] = acc[i][j] + bv;
            }
        }
    }
}

// ---------------------------------------------------------------------------
// K2: Viterbi forward. One block (1 wave) per batch. lane = 'to' tag.
// T row in registers; state in LDS; bp bytes to global; final state to global.
// ---------------------------------------------------------------------------
__global__ __launch_bounds__(64) void viterbi_fwd(
    const float* __restrict__ emit, const int* __restrict__ masks,
    const float* __restrict__ T, unsigned char* __restrict__ bp,
    float* __restrict__ sfin)
{
    const int b  = blockIdx.x;
    const int to = threadIdx.x;
    const int toc = (to < CTAGS) ? to : (CTAGS - 1);

    __shared__ float ss[56];

    float Trow[CTAGS];
#pragma unroll
    for (int f = 0; f < CTAGS; ++f) Trow[f] = T[toc * CTAGS + f];

    if (to < 56) ss[to] = (to == START_IDX) ? 0.f : -10000.f;
    __syncthreads();

    const float* eb = emit + (size_t)b * SEQL * CTAGS;
    const int*   mb = masks + (size_t)b * SEQL;

    float e_cur = (to < CTAGS) ? eb[to] : 0.f;
    int   m_cur = mb[0];
    float newv  = 0.f;

    for (int t = 0; t < SEQL; ++t) {
        // prefetch next step's emission + mask
        float e_nxt = 0.f;
        int   m_nxt = 1;
        if (t + 1 < SEQL) {
            if (to < CTAGS) e_nxt = eb[(size_t)(t + 1) * CTAGS + to];
            m_nxt = mb[t + 1];
        }

        // read state into registers (13 x float4)
        float sreg[CTAGS];
#pragma unroll
        for (int fq = 0; fq < 13; ++fq) {
            float4 v = *(const float4*)&ss[fq * 4];
            sreg[fq * 4 + 0] = v.x;
            sreg[fq * 4 + 1] = v.y;
            sreg[fq * 4 + 2] = v.z;
            sreg[fq * 4 + 3] = v.w;
        }

        float m = NEG_INF;
        int bpi = 0;
#pragma unroll
        for (int f = 0; f < CTAGS; ++f) {
            float v = sreg[f] + Trow[f];
            if (v > m) { m = v; bpi = f; }   // strict > : first max wins
        }

        float sown = sreg[toc];
        newv = m_cur ? (m + e_cur) : sown;

        if (to < CTAGS)
            bp[(size_t)t * (BATCH * CTAGS) + b * CTAGS + to] = (unsigned char)bpi;

        __syncthreads();
        if (to < CTAGS) ss[to] = newv;
        __syncthreads();

        e_cur = e_nxt;
        m_cur = m_nxt;
    }

    if (to < CTAGS) sfin[b * CTAGS + to] = newv;
}

// ---------------------------------------------------------------------------
// K3: backtrack. One block (1 wave) per batch. Stage bp rows + masks in LDS,
// wave-argmax the final scores, then lane-redundant LDS pointer chase.
// out[0..127] = best_score ; out[128 + b*512 + t] = (float)path[b][t]
// ---------------------------------------------------------------------------
__global__ __launch_bounds__(64) void viterbi_bt(
    const unsigned char* __restrict__ bp, const float* __restrict__ sfin,
    const float* __restrict__ T, const int* __restrict__ masks,
    float* __restrict__ out)
{
    const int b   = blockIdx.x;
    const int tid = threadIdx.x;

    __shared__ __align__(16) unsigned char bpl[SEQL * CTAGS]; // 26624 B
    __shared__ int ml[SEQL];                                  // 2048 B

    // stage bp for this batch: 512 rows x 13 dwords
    for (int idx = tid; idx < SEQL * 13; idx += 64) {
        int row = idx / 13;
        int dw  = idx - row * 13;
        uint32_t v = *(const uint32_t*)(bp + (size_t)row * (BATCH * CTAGS) + b * CTAGS + dw * 4);
        ((uint32_t*)bpl)[idx] = v;
    }
    for (int i = tid; i < SEQL; i += 64) ml[i] = masks[(size_t)b * SEQL + i];

    // final = sfin + T[stop] ; wave argmax with first-index tiebreak
    float v = NEG_INF;
    if (tid < CTAGS) v = sfin[b * CTAGS + tid] + T[STOP_IDX * CTAGS + tid];
    int idxv = tid;
    __syncthreads();

#pragma unroll
    for (int s = 1; s < 64; s <<= 1) {
        float ov = __shfl_xor(v, s);
        int   oi = __shfl_xor(idxv, s);
        if (ov > v || (ov == v && oi < idxv)) { v = ov; idxv = oi; }
    }

    if (tid == 0) out[b] = v;

    int cur = idxv;
    float* po = out + BATCH + (size_t)b * SEQL;
    if (tid == 0) po[SEQL - 1] = (float)cur;

    for (int i = SEQL - 2; i >= 0; --i) {
        int nxt = bpl[(i + 1) * CTAGS + cur];
        cur = ml[i] ? nxt : cur;
        if (tid == 0) po[i] = (float)cur;
    }
}

// ---------------------------------------------------------------------------
extern "C" void kernel_launch(void* const* d_in, const int* in_sizes, int n_in,
                              void* d_out, int out_size, void* d_ws, size_t ws_size,
                              hipStream_t stream)
{
    const float* features = (const float*)d_in[0];
    const int*   masks    = (const int*)d_in[1];
    const float* W        = (const float*)d_in[2];
    const float* bias     = (const float*)d_in[3];
    const float* T        = (const float*)d_in[4];

    float* out = (float*)d_out;

    // workspace layout
    const size_t emit_bytes = (size_t)BATCH * SEQL * CTAGS * sizeof(float); // 13631488
    const size_t bp_bytes   = (size_t)SEQL * BATCH * CTAGS;                 // 3407872
    float*         emit = (float*)d_ws;
    unsigned char* bpws = (unsigned char*)d_ws + emit_bytes;
    float*         sfin = (float*)((unsigned char*)d_ws + emit_bytes + bp_bytes);

    // K1: emission GEMM
    emit_gemm<<<(BATCH * SEQL) / BM, 256, 0, stream>>>(features, W, bias, emit);

    // K2: forward scan
    viterbi_fwd<<<BATCH, 64, 0, stream>>>(emit, masks, T, bpws, sfin);

    // K3: backtrack
    viterbi_bt<<<BATCH, 64, 0, stream>>>(bpws, sfin, T, masks, out);
}

// Round 2
// 392.392 us; speedup vs baseline: 1.9035x; 1.9035x over previous
//
#include <hip/hip_runtime.h>
#include <stdint.h>

#define BATCH 128
#define SEQL  512
#define FDIM  768
#define CTAGS 52
#define START_IDX 50
#define STOP_IDX  51
#define NEG_INF (-3.0e38f)

// ---------------------------------------------------------------------------
// K1: emission GEMM  emit[(b*L+l)][c] = sum_f features[b,l,f] * W[c,f] + bias[c]
// Tiled fp32: BM=64 rows, BN=64 (tags padded 52->64), BK=64.  (unchanged)
// ---------------------------------------------------------------------------
#define BM 64
#define BN 64
#define BK 64

__global__ __launch_bounds__(256) void emit_gemm(
    const float* __restrict__ F, const float* __restrict__ W,
    const float* __restrict__ bias, float* __restrict__ emit)
{
    __shared__ float Fs[BM][BK + 4];
    __shared__ float Ws[BN][BK + 4];

    const int tid  = threadIdx.x;
    const int row0 = blockIdx.x * BM;
    const int tr = tid >> 4;   // 0..15
    const int tc = tid & 15;   // 0..15

    float acc[4][4];
#pragma unroll
    for (int i = 0; i < 4; ++i)
#pragma unroll
        for (int j = 0; j < 4; ++j) acc[i][j] = 0.f;

    for (int k0 = 0; k0 < FDIM; k0 += BK) {
#pragma unroll
        for (int i = 0; i < 4; ++i) {
            int rr = tr + 16 * i;
            float4 fv = *(const float4*)&F[(size_t)(row0 + rr) * FDIM + k0 + tc * 4];
            *(float4*)&Fs[rr][tc * 4] = fv;
            float4 wv;
            if (rr < CTAGS) wv = *(const float4*)&W[(size_t)rr * FDIM + k0 + tc * 4];
            else            wv = make_float4(0.f, 0.f, 0.f, 0.f);
            *(float4*)&Ws[rr][tc * 4] = wv;
        }
        __syncthreads();

#pragma unroll
        for (int kk = 0; kk < BK; kk += 4) {
            float4 a[4], bb[4];
#pragma unroll
            for (int i = 0; i < 4; ++i) a[i]  = *(const float4*)&Fs[tr + 16 * i][kk];
#pragma unroll
            for (int j = 0; j < 4; ++j) bb[j] = *(const float4*)&Ws[tc + 16 * j][kk];
#pragma unroll
            for (int i = 0; i < 4; ++i)
#pragma unroll
                for (int j = 0; j < 4; ++j) {
                    acc[i][j] = fmaf(a[i].x, bb[j].x, acc[i][j]);
                    acc[i][j] = fmaf(a[i].y, bb[j].y, acc[i][j]);
                    acc[i][j] = fmaf(a[i].z, bb[j].z, acc[i][j]);
                    acc[i][j] = fmaf(a[i].w, bb[j].w, acc[i][j]);
                }
        }
        __syncthreads();
    }

#pragma unroll
    for (int j = 0; j < 4; ++j) {
        int c = tc + 16 * j;
        if (c < CTAGS) {
            float bv = bias[c];
#pragma unroll
            for (int i = 0; i < 4; ++i) {
                int r = row0 + tr + 16 * i;
                emit[(size_t)r * CTAGS + c] = acc[i][j] + bv;
            }
        }
    }
}

// ---------------------------------------------------------------------------
// K2 (fused): Viterbi forward + backtrack. One block = one wave per batch.
// lane = 'to' tag. State lives in lane registers; broadcast via v_readlane
// (wave-uniform -> SGPRs). NO barriers / NO global stores in the hot loop.
// Backpointers in LDS; chase + path write fused at the end.
// ---------------------------------------------------------------------------
__global__ __launch_bounds__(64) void viterbi_fused(
    const float* __restrict__ emit, const int* __restrict__ masks,
    const float* __restrict__ T, float* __restrict__ out)
{
    const int b  = blockIdx.x;
    const int to = threadIdx.x;
    const int toc = (to < CTAGS) ? to : (CTAGS - 1);

    __shared__ unsigned char bpl[SEQL * 64];   // 32 KB backpointers
    __shared__ int           mlds[SEQL];       // 2 KB masks
    __shared__ unsigned char pathb[SEQL];      // path bytes

    // transition row for this 'to' in registers
    float Trow[CTAGS];
#pragma unroll
    for (int f = 0; f < CTAGS; ++f) Trow[f] = T[toc * CTAGS + f];
    const float tstop = T[STOP_IDX * CTAGS + toc];

    const float* eb = emit  + (size_t)b * SEQL * CTAGS;
    const int*   mb = masks + (size_t)b * SEQL;

    // init state: lane f holds s[f]
    float cur = (to == START_IDX) ? 0.0f : -10000.0f;

    float e_cur = eb[toc];
    int   m_cur = mb[0];

    for (int t = 0; t < SEQL; ++t) {
        // prefetch next emission + mask (consumed next iteration; hidden
        // under ~500 cycles of VALU work since there is no barrier/waitcnt
        // drain anywhere in this loop)
        float e_nxt = 0.0f;
        int   m_nxt = 0;
        if (t + 1 < SEQL) {
            e_nxt = eb[(size_t)(t + 1) * CTAGS + toc];
            m_nxt = mb[t + 1];
        }

        // broadcast state to all lanes via readlane (uniform -> SGPR)
        const unsigned cu = __float_as_uint(cur);
        float a[CTAGS];
#pragma unroll
        for (int f = 0; f < CTAGS; ++f) {
            float sf = __uint_as_float(__builtin_amdgcn_readlane((int)cu, f));
            a[f] = sf + Trow[f];
        }

        // ---- max via v_max3 tree: 52 -> 18 -> 6 -> 1  (depth 4) ----
        float l1[18];
#pragma unroll
        for (int i = 0; i < 17; ++i)
            l1[i] = fmaxf(fmaxf(a[3 * i], a[3 * i + 1]), a[3 * i + 2]);
        l1[17] = a[51];
        float l2[6];
#pragma unroll
        for (int i = 0; i < 6; ++i)
            l2[i] = fmaxf(fmaxf(l1[3 * i], l1[3 * i + 1]), l1[3 * i + 2]);
        const float m = fmaxf(fmaxf(fmaxf(l2[0], l2[1]), l2[2]),
                              fmaxf(fmaxf(l2[3], l2[4]), l2[5]));

        // ---- first index with a[f] == m via min tree ----
        int c1[18];
#pragma unroll
        for (int i = 0; i < 17; ++i) {
            int x = (a[3 * i]     == m) ? (3 * i)     : 63;
            int y = (a[3 * i + 1] == m) ? (3 * i + 1) : 63;
            int z = (a[3 * i + 2] == m) ? (3 * i + 2) : 63;
            c1[i] = min(min(x, y), z);
        }
        c1[17] = (a[51] == m) ? 51 : 63;
        int c2[6];
#pragma unroll
        for (int i = 0; i < 6; ++i)
            c2[i] = min(min(c1[3 * i], c1[3 * i + 1]), c1[3 * i + 2]);
        const int idx = min(min(min(c2[0], c2[1]), c2[2]),
                            min(min(c2[3], c2[4]), c2[5]));

        // backpointer to LDS (stride 64 to keep addressing trivial)
        bpl[t * 64 + to] = (unsigned char)idx;

        // masked update (strictly register ops)
        cur = m_cur ? (m + e_cur) : cur;

        e_cur = e_nxt;
        m_cur = m_nxt;
    }

    // stage masks for the chase
    for (int i = to; i < SEQL; i += 64) mlds[i] = mb[i];
    __syncthreads();

    // final scores + wave argmax (first-index tiebreak)
    float v   = (to < CTAGS) ? (cur + tstop) : NEG_INF;
    int  bidx = to;
#pragma unroll
    for (int s = 1; s < 64; s <<= 1) {
        float ov = __shfl_xor(v, s);
        int   oi = __shfl_xor(bidx, s);
        if (ov > v || (ov == v && oi < bidx)) { v = ov; bidx = oi; }
    }
    if (to == 0) out[b] = v;

    // backtrack chase (lane-redundant; LDS broadcast reads)
    int c = bidx;
    if (to == 0) pathb[SEQL - 1] = (unsigned char)c;
    for (int i = SEQL - 2; i >= 0; --i) {
        int nxt = bpl[(i + 1) * 64 + c];
        c = mlds[i] ? nxt : c;
        if (to == 0) pathb[i] = (unsigned char)c;
    }
    __syncthreads();

    // coalesced path write
    float* po = out + BATCH + (size_t)b * SEQL;
#pragma unroll
    for (int i = 0; i < 8; ++i)
        po[i * 64 + to] = (float)pathb[i * 64 + to];
}

// ---------------------------------------------------------------------------
extern "C" void kernel_launch(void* const* d_in, const int* in_sizes, int n_in,
                              void* d_out, int out_size, void* d_ws, size_t ws_size,
                              hipStream_t stream)
{
    const float* features = (const float*)d_in[0];
    const int*   masks    = (const int*)d_in[1];
    const float* W        = (const float*)d_in[2];
    const float* bias     = (const float*)d_in[3];
    const float* T        = (const float*)d_in[4];

    float* out  = (float*)d_out;
    float* emit = (float*)d_ws;   // 128*512*52*4 = 13.6 MB

    emit_gemm<<<(BATCH * SEQL) / BM, 256, 0, stream>>>(features, W, bias, emit);
    viterbi_fused<<<BATCH, 64, 0, stream>>>(emit, masks, T, out);
}